// Round 1
// baseline (107.032 us; speedup 1.0000x reference)
//
#include <hip/hip_runtime.h>
#include <math.h>

// Problem constants (B=2, D=512, K=32, H=W=64 -> N=4096)
#define B_DIM 2
#define D_DIM 512
#define K_DIM 32
#define N_DIM 4096

// Workspace layout (floats):
//   [0:64)    nsq[b][k]
//   [64]      cnt (int, grid-sync counter for k3)
//   [64:128)  pad
//   [128:128+32768)  T[b][d][k]   (fp32 atomic accumulate by k2)
//   then      Mp[b*256+tile][k]   (512*32, per-block Q mass from k1)
#define WS_T_OFF   128
#define WS_MP_OFF  (128 + B_DIM * D_DIM * K_DIM)

// ---------------------------------------------------------------------------
// K1: distances + softmax Q + per-block Q-mass partials. Also zeroes T/nsq/cnt
// (consumed by later dispatches; stream order guarantees visibility).
// dist[b,n,k] = sum_d A*x^2 + B2*x + A*c^2,  A = s^2, B2 = -2 s^2 c
// grid = 512 = B * 256 n-tiles of 16; block = 512 threads (8 waves).
// Wave kw owns k-slice [4kw,4kw+4); lane dp owns d {4dp..+3, 256+4dp..+3}.
// Register tables are [8 d][4 k] = 68 persistent VGPRs -> target <=128 VGPR
// so launch_bounds(512,4) gives 16 waves/CU (2 blocks; LDS 70KB*2 <= 160KB).
// ---------------------------------------------------------------------------
__global__ __launch_bounds__(512, 4)
void k_dist_q(const float* __restrict__ X, const float* __restrict__ CW,
              const float* __restrict__ SC, float* __restrict__ Qout,
              float* __restrict__ W)
{
    __shared__ __align__(16) float xlds[16 * 516];     // [n 16][d 512, stride 516]
    __shared__ __align__(16) float red[16 * 16 * 36];  // [n 16][i 16][k 32 +4]

    const int tid = threadIdx.x;
    const int b  = blockIdx.x >> 8;
    const int n0 = (blockIdx.x & 255) << 4;   // 16 n per block
    const int dp = tid & 63;
    const int kw = tid >> 6;                  // wave id 0..7
    const int k0 = kw << 2;                   // 4 k per thread

    // ---- zero T (this block's 64-float slice) + nsq/cnt (block 0) ----
    {
        float* T = W + WS_T_OFF;
        if (tid < 64) T[(blockIdx.x << 6) + tid] = 0.f;
        if (blockIdx.x == 0 && tid >= 64 && tid < 129) W[tid - 64] = 0.f;
    }

    // ---- stage 16 n x 512 d (transposed to [n][d]); 64-B coalesced reads ----
    const float* xsrc = X + (size_t)b * D_DIM * N_DIM + n0;
#pragma unroll
    for (int j = 0; j < 4; ++j) {
        const int d  = (tid >> 2) + (j << 7);
        const int n4 = (tid & 3) << 2;
        float4 v = *(const float4*)(xsrc + (size_t)d * N_DIM + n4);
        xlds[(n4 + 0) * 516 + d] = v.x;
        xlds[(n4 + 1) * 516 + d] = v.y;
        xlds[(n4 + 2) * 516 + d] = v.z;
        xlds[(n4 + 3) * 516 + d] = v.w;
    }

    // ---- prologue: register tables (overlaps other waves' staging) ----
    float cv[4][8];                    // cv[kk][dd] = codeword value
#pragma unroll
    for (int kk = 0; kk < 4; ++kk) {
        const float* cr = CW + (k0 + kk) * D_DIM + (dp << 2);
        float4 c0 = *(const float4*)(cr);
        float4 c1 = *(const float4*)(cr + 256);
        cv[kk][0] = c0.x; cv[kk][1] = c0.y; cv[kk][2] = c0.z; cv[kk][3] = c0.w;
        cv[kk][4] = c1.x; cv[kk][5] = c1.y; cv[kk][6] = c1.z; cv[kk][7] = c1.w;
    }
    float Areg[8][4], Breg[8][4], ckp[4];
#pragma unroll
    for (int kk = 0; kk < 4; ++kk) ckp[kk] = 0.f;
#pragma unroll
    for (int dd = 0; dd < 8; ++dd) {
        const int d = (dd < 4) ? ((dp << 2) + dd) : (256 + (dp << 2) + (dd - 4));
        float4 s4 = *(const float4*)(SC + d * K_DIM + k0);
        float sv[4] = {s4.x, s4.y, s4.z, s4.w};
#pragma unroll
        for (int kk = 0; kk < 4; ++kk) {
            float c = cv[kk][dd];
            float a = sv[kk] * sv[kk];
            float t = a * c;
            Areg[dd][kk] = a;
            Breg[dd][kk] = -2.f * t;
            ckp[kk] = fmaf(t, c, ckp[kk]);
        }
    }
    __syncthreads();

    // ---- main: 16 n, 64 FMA-pairs each ----
#pragma unroll
    for (int n = 0; n < 16; ++n) {
        float dist[4] = {ckp[0], ckp[1], ckp[2], ckp[3]};
        float4 xa = *(const float4*)(&xlds[n * 516 + (dp << 2)]);
        float4 xb = *(const float4*)(&xlds[n * 516 + (dp << 2) + 256]);
        float xv[8] = {xa.x, xa.y, xa.z, xa.w, xb.x, xb.y, xb.z, xb.w};
#pragma unroll
        for (int dd = 0; dd < 8; ++dd) {
            const float x  = xv[dd];
            const float x2 = x * x;
#pragma unroll
            for (int kk = 0; kk < 4; ++kk) {
                dist[kk] = fmaf(Areg[dd][kk], x2, dist[kk]);
                dist[kk] = fmaf(Breg[dd][kk], x,  dist[kk]);
            }
        }
#pragma unroll
        for (int kk = 0; kk < 4; ++kk) {
            dist[kk] += __shfl_xor(dist[kk], 32);
            dist[kk] += __shfl_xor(dist[kk], 16);
        }
        if (dp < 16)
            *(float4*)(&red[(n * 16 + dp) * 36 + k0]) =
                make_float4(dist[0], dist[1], dist[2], dist[3]);
    }
    __syncthreads();

    // ---- reduce 16 partials + softmax over k (32-lane groups), 1 pass ----
    const int n = tid >> 5;
    const int k = tid & 31;
    float dsum = 0.f;
#pragma unroll
    for (int i = 0; i < 16; ++i) dsum += red[(n * 16 + i) * 36 + k];
    float m = dsum;
#pragma unroll
    for (int mk = 16; mk >= 1; mk >>= 1)
        m = fminf(m, __shfl_xor(m, mk));
    float e = __expf(-0.5f * (dsum - m));
    float ssum = e;
#pragma unroll
    for (int mk = 16; mk >= 1; mk >>= 1)
        ssum += __shfl_xor(ssum, mk);
    float q = __fdividef(e, ssum);
    Qout[((size_t)b * N_DIM + n0 + n) * K_DIM + k] = q;

    // ---- block's Q-mass partial: Mp[block][k] = sum over 16 n of Q ----
    __syncthreads();
    xlds[n * 33 + k] = q;              // reuse xlds as mq[16][33]
    __syncthreads();
    if (tid < K_DIM) {
        float t = 0.f;
#pragma unroll
        for (int i = 0; i < 16; ++i) t += xlds[i * 33 + tid];
        W[WS_MP_OFF + blockIdx.x * K_DIM + tid] = t;
    }
}

// ---------------------------------------------------------------------------
// K2: T[b,d,k] += sum_n Q[b,n,k] * X[b,d,n], n split 32 ways; fp32 atomicAdd
// into T (zeroed by k1). grid = 512 = b(2) x dtile(8 of 64 d) x ns(32 of 128 n).
// ---------------------------------------------------------------------------
__global__ __launch_bounds__(256, 2)
void k_tacc(const float* __restrict__ X, const float* __restrict__ Qin,
            float* __restrict__ W)
{
    __shared__ __align__(16) float Xs[64 * 68];        // [d 64][n 64 +4]
    __shared__ __align__(16) float Qs[32 * 68];        // [k 32][n 64 +4]
    __shared__ __align__(16) float red4[4 * 64 * 36];  // [wave][d 64][k 32 +4]

    const int tid = threadIdx.x;
    const int bid = blockIdx.x;
    const int ns = bid & 31;
    const int dt = (bid >> 5) & 7;
    const int b  = bid >> 8;
    const int nsub = tid >> 5;
    const int dp = tid & 7;
    const int kp = (tid >> 3) & 3;
    const int wv = tid >> 6;

    float acc[8][8];
#pragma unroll
    for (int i = 0; i < 8; ++i)
#pragma unroll
        for (int j = 0; j < 8; ++j) acc[i][j] = 0.f;

    const float* xsrc = X + ((size_t)b * D_DIM + dt * 64) * N_DIM + ns * 128;
    const float* qsrc = Qin + ((size_t)b * N_DIM + ns * 128) * K_DIM;

    for (int ch = 0; ch < 2; ++ch) {   // 2 chunks of 64 n
        __syncthreads();
#pragma unroll
        for (int i = 0; i < 4; ++i) {  // stage Xs: 64 d x 64 n
            int flat4 = tid + (i << 8);
            int row = flat4 >> 4;
            int c4  = (flat4 & 15) << 2;
            float4 v = *(const float4*)(xsrc + (size_t)row * N_DIM + (ch << 6) + c4);
            *(float4*)(&Xs[row * 68 + c4]) = v;
        }
#pragma unroll
        for (int i = 0; i < 2; ++i) {  // stage Qs transposed: [k][n]
            int flat4 = tid + (i << 8);
            int nn = flat4 >> 3;
            int k4 = (flat4 & 7) << 2;
            float4 v = *(const float4*)(qsrc + ((ch << 6) + nn) * K_DIM + k4);
            Qs[(k4 + 0) * 68 + nn] = v.x;
            Qs[(k4 + 1) * 68 + nn] = v.y;
            Qs[(k4 + 2) * 68 + nn] = v.z;
            Qs[(k4 + 3) * 68 + nn] = v.w;
        }
        __syncthreads();
#pragma unroll
        for (int s = 0; s < 2; ++s) {
            const int nb = (nsub << 3) + (s << 2);
            float4 xr[8], qr[8];
#pragma unroll
            for (int i = 0; i < 8; ++i)
                xr[i] = *(const float4*)(&Xs[(dp + (i << 3)) * 68 + nb]);
#pragma unroll
            for (int j = 0; j < 8; ++j)
                qr[j] = *(const float4*)(&Qs[(kp + (j << 2)) * 68 + nb]);
#pragma unroll
            for (int i = 0; i < 8; ++i)
#pragma unroll
                for (int j = 0; j < 8; ++j) {
                    acc[i][j] = fmaf(xr[i].x, qr[j].x, acc[i][j]);
                    acc[i][j] = fmaf(xr[i].y, qr[j].y, acc[i][j]);
                    acc[i][j] = fmaf(xr[i].z, qr[j].z, acc[i][j]);
                    acc[i][j] = fmaf(xr[i].w, qr[j].w, acc[i][j]);
                }
        }
    }
    // pair-reduce nsub (2w, 2w+1) via shfl, then per-wave slabs (no atomics)
    __syncthreads();
#pragma unroll
    for (int i = 0; i < 8; ++i)
#pragma unroll
        for (int j = 0; j < 8; ++j)
            acc[i][j] += __shfl_xor(acc[i][j], 32);
    if ((tid & 32) == 0) {
#pragma unroll
        for (int i = 0; i < 8; ++i)
#pragma unroll
            for (int j = 0; j < 8; ++j)
                red4[(wv * 64 + dp + (i << 3)) * 36 + kp + (j << 2)] = acc[i][j];
    }
    __syncthreads();
    // sum 4 wave slabs, atomically accumulate 64x32 tile into T (coalesced)
    float* T = W + WS_T_OFF + (((size_t)b * D_DIM + dt * 64) * K_DIM);
#pragma unroll
    for (int e = 0; e < 8; ++e) {
        int flat = tid + (e << 8);          // 2048 cells
        int dl = flat >> 5;
        int k  = flat & 31;
        float s = red4[(0 * 64 + dl) * 36 + k] + red4[(1 * 64 + dl) * 36 + k]
                + red4[(2 * 64 + dl) * 36 + k] + red4[(3 * 64 + dl) * 36 + k];
        atomicAdd(&T[dl * K_DIM + k], s);
    }
}

// ---------------------------------------------------------------------------
// K3 (merged zpre+zfin): M from Mp partials, z = s*(T/M - c) in registers,
// nsq atomics, counter-based grid spin (128 small blocks -> co-resident),
// then Z = z * rsqrt(nsq). grid 128 = b(2) x 64 d-slices of 8.
// ---------------------------------------------------------------------------
__global__ __launch_bounds__(256)
void k_zfin(const float* __restrict__ CW, const float* __restrict__ SC,
            float* __restrict__ W, float* __restrict__ Z)
{
    __shared__ float mred[8][33];
    __shared__ float Msh[K_DIM];
    __shared__ float part[8][33];

    const int tid = threadIdx.x;
    const int b  = blockIdx.x >> 6;
    const int ds = blockIdx.x & 63;
    const int g  = tid >> 5;
    const int d  = (ds << 3) + g;
    const int k  = tid & 31;

    float* nsq = W;
    int*   cnt = (int*)(W + 64);
    const float* T  = W + WS_T_OFF;
    const float* Mp = W + WS_MP_OFF;

    // M[b,k] = sum over 256 n-tiles of Mp (L2-hot, coalesced across k)
    float pm = 0.f;
#pragma unroll
    for (int i = 0; i < 32; ++i)
        pm += Mp[((b << 8) + (g << 5) + i) * K_DIM + k];
    mred[g][k] = pm;
    __syncthreads();
    if (tid < K_DIM) {
        float t = 0.f;
#pragma unroll
        for (int i = 0; i < 8; ++i) t += mred[i][tid];
        Msh[tid] = t;
    }
    __syncthreads();
    const float m = Msh[k];

    const float t = T[((size_t)(b * D_DIM + d)) * K_DIM + k];
    const float c = CW[k * D_DIM + d];
    const float s = SC[d * K_DIM + k];
    const float z = s * (t / m - c);

    part[g][k] = z * z;
    __syncthreads();
    if (tid < K_DIM) {
        float q = 0.f;
#pragma unroll
        for (int i = 0; i < 8; ++i) q += part[i][tid];
        atomicAdd(&nsq[(b << 5) + tid], q);
    }

    // ---- grid sync: all 128 blocks' nsq contributions must land ----
    __threadfence();
    __syncthreads();
    if (tid == 0) {
        __hip_atomic_fetch_add(cnt, 1, __ATOMIC_ACQ_REL, __HIP_MEMORY_SCOPE_AGENT);
        while (__hip_atomic_load(cnt, __ATOMIC_ACQUIRE, __HIP_MEMORY_SCOPE_AGENT)
               < (int)gridDim.x)
            __builtin_amdgcn_s_sleep(2);
    }
    __syncthreads();

    const float nv = __hip_atomic_load(&nsq[(b << 5) + k], __ATOMIC_RELAXED,
                                       __HIP_MEMORY_SCOPE_AGENT);
    Z[((size_t)(b * D_DIM + d)) * K_DIM + k] = z * rsqrtf(nv);
}

extern "C" void kernel_launch(void* const* d_in, const int* in_sizes, int n_in,
                              void* d_out, int out_size, void* d_ws, size_t ws_size,
                              hipStream_t stream)
{
    const float* X  = (const float*)d_in[0];   // [2,512,64,64]
    const float* CW = (const float*)d_in[1];   // [32,512]
    const float* SC = (const float*)d_in[2];   // [512,32]
    float* Z = (float*)d_out;                              // [2,512,32]
    float* Q = (float*)d_out + B_DIM * D_DIM * K_DIM;      // [2,4096,32]
    float* W = (float*)d_ws;

    k_dist_q<<<512, 512, 0, stream>>>(X, CW, SC, Q, W);
    k_tacc  <<<512, 256, 0, stream>>>(X, Q, W);
    k_zfin  <<<128, 256, 0, stream>>>(CW, SC, W, Z);
}

// Round 2
// 106.988 us; speedup vs baseline: 1.0004x; 1.0004x over previous
//
#include <hip/hip_runtime.h>
#include <math.h>

// Problem constants (B=2, D=512, K=32, H=W=64 -> N=4096)
#define B_DIM 2
#define D_DIM 512
#define K_DIM 32
#define N_DIM 4096

// Workspace layout (floats):
//   [0:64)     nsq[b][k]        (atomicAdd by k3 blocks; zeroed by k1 blk 0)
//   [64]       cnt              (grid-sync counter for k3; zeroed by k1 blk 0)
//   [65:128)   pad
//   [128:128+16384)  Mp[b*256+tile][k]  (per-block Q mass from k1)
//   then       TP[ns*2+b][d][k]         (32 n-slice partials from k2, 4 MB)
#define WS_MP_OFF  128
#define WS_TP_OFF  (128 + 512 * K_DIM)

// ---------------------------------------------------------------------------
// K1: distances + softmax Q + per-block Q-mass partial. Baseline structure
// (256 thr, 8 k/thread, verified 96.9 us) + Mp write reusing freed xlds.
// dist[b,n,k] = sum_d A*x^2 + B2*x + A*c^2,  A = s^2, B2 = -2 s^2 c
// grid = 512 = B * 256 n-tiles of 16; block = 256 threads (4 waves)
// ---------------------------------------------------------------------------
__global__ __launch_bounds__(256, 2)
void k_dist_q(const float* __restrict__ X, const float* __restrict__ CW,
              const float* __restrict__ SC, float* __restrict__ Qout,
              float* __restrict__ W)
{
    __shared__ __align__(16) float xlds[16 * 516];     // [n 16][d 512, stride 516]
    __shared__ __align__(16) float red[16 * 16 * 36];  // [n 16][i 16][k 32 +4]

    const int tid = threadIdx.x;
    const int b  = blockIdx.x >> 8;
    const int n0 = (blockIdx.x & 255) << 4;   // 16 n per block
    const int dp = tid & 63;
    const int kp = tid >> 6;
    const int k0 = kp << 3;

    // zero nsq (64) + cnt (1); consumed 2 dispatches later (stream-ordered)
    if (blockIdx.x == 0 && tid < 65) W[tid] = 0.f;

    // ---- stage 16 n x 512 d (transposed to [n][d]); 64-B coalesced reads ----
    const float* xsrc = X + (size_t)b * D_DIM * N_DIM + n0;
#pragma unroll
    for (int j = 0; j < 8; ++j) {
        const int d  = (tid >> 2) + (j << 6);
        const int n4 = (tid & 3) << 2;
        float4 v = *(const float4*)(xsrc + (size_t)d * N_DIM + n4);
        xlds[(n4 + 0) * 516 + d] = v.x;
        xlds[(n4 + 1) * 516 + d] = v.y;
        xlds[(n4 + 2) * 516 + d] = v.z;
        xlds[(n4 + 3) * 516 + d] = v.w;
    }

    // ---- prologue: register tables (overlaps other waves' staging) ----
    float cv[8][8];                    // cv[kk][dd] = codeword value
#pragma unroll
    for (int kk = 0; kk < 8; ++kk) {
        const float* cr = CW + (k0 + kk) * D_DIM + (dp << 2);
        float4 c0 = *(const float4*)(cr);
        float4 c1 = *(const float4*)(cr + 256);
        cv[kk][0] = c0.x; cv[kk][1] = c0.y; cv[kk][2] = c0.z; cv[kk][3] = c0.w;
        cv[kk][4] = c1.x; cv[kk][5] = c1.y; cv[kk][6] = c1.z; cv[kk][7] = c1.w;
    }
    float Areg[8][8], Breg[8][8], ckp[8];
#pragma unroll
    for (int kk = 0; kk < 8; ++kk) ckp[kk] = 0.f;
#pragma unroll
    for (int dd = 0; dd < 8; ++dd) {
        const int d = (dd < 4) ? ((dp << 2) + dd) : (256 + (dp << 2) + (dd - 4));
        float4 s0 = *(const float4*)(SC + d * K_DIM + k0);
        float4 s1 = *(const float4*)(SC + d * K_DIM + k0 + 4);
        float sv[8] = {s0.x, s0.y, s0.z, s0.w, s1.x, s1.y, s1.z, s1.w};
#pragma unroll
        for (int kk = 0; kk < 8; ++kk) {
            float c = cv[kk][dd];
            float a = sv[kk] * sv[kk];
            Areg[dd][kk] = a;
            Breg[dd][kk] = -2.f * a * c;
            ckp[kk] = fmaf(a * c, c, ckp[kk]);
        }
    }
    __syncthreads();

    // ---- main: 16 n, 128 FMA-pairs each ----
#pragma unroll
    for (int n = 0; n < 16; ++n) {
        float dist[8];
#pragma unroll
        for (int kk = 0; kk < 8; ++kk) dist[kk] = ckp[kk];
        float4 xa = *(const float4*)(&xlds[n * 516 + (dp << 2)]);
        float4 xb = *(const float4*)(&xlds[n * 516 + (dp << 2) + 256]);
        float xv[8] = {xa.x, xa.y, xa.z, xa.w, xb.x, xb.y, xb.z, xb.w};
#pragma unroll
        for (int dd = 0; dd < 8; ++dd) {
            const float x  = xv[dd];
            const float x2 = x * x;
#pragma unroll
            for (int kk = 0; kk < 8; ++kk) {
                dist[kk] = fmaf(Areg[dd][kk], x2, dist[kk]);
                dist[kk] = fmaf(Breg[dd][kk], x,  dist[kk]);
            }
        }
#pragma unroll
        for (int kk = 0; kk < 8; ++kk) {
            dist[kk] += __shfl_xor(dist[kk], 32);
            dist[kk] += __shfl_xor(dist[kk], 16);
        }
        if (dp < 16) {
            float* r = &red[(n * 16 + dp) * 36 + k0];
            *(float4*)(r)     = make_float4(dist[0], dist[1], dist[2], dist[3]);
            *(float4*)(r + 4) = make_float4(dist[4], dist[5], dist[6], dist[7]);
        }
    }
    __syncthreads();

    // ---- reduce 16 partials + softmax over k (32-lane groups), 2 passes ----
    // xlds is dead past this sync: reuse as mq[16][33] for the Q-mass partial.
#pragma unroll
    for (int h = 0; h < 2; ++h) {
        const int n = (tid >> 5) + (h << 3);
        const int k = tid & 31;
        float dsum = 0.f;
#pragma unroll
        for (int i = 0; i < 16; ++i) dsum += red[(n * 16 + i) * 36 + k];
        float m = dsum;
#pragma unroll
        for (int mk = 16; mk >= 1; mk >>= 1)
            m = fminf(m, __shfl_xor(m, mk));
        float e = __expf(-0.5f * (dsum - m));
        float ssum = e;
#pragma unroll
        for (int mk = 16; mk >= 1; mk >>= 1)
            ssum += __shfl_xor(ssum, mk);
        float q = __fdividef(e, ssum);
        Qout[((size_t)b * N_DIM + n0 + n) * K_DIM + k] = q;
        xlds[n * 33 + k] = q;
    }
    __syncthreads();
    if (tid < K_DIM) {
        float t = 0.f;
#pragma unroll
        for (int i = 0; i < 16; ++i) t += xlds[i * 33 + tid];
        W[WS_MP_OFF + blockIdx.x * K_DIM + tid] = t;
    }
}

// ---------------------------------------------------------------------------
// K2: T partials. T[b,d,k] = sum_n Q[b,n,k] * X[b,d,n], n split 32 ways.
// grid = 512 = b(2) x dtile(8 of 64 d) x ns(32 of 128 n). Plain stores to TP
// (no atomics). Baseline structure, Mpart tail removed (Mp comes from k1).
// ---------------------------------------------------------------------------
__global__ __launch_bounds__(256, 2)
void k_tpart(const float* __restrict__ X, const float* __restrict__ Qin,
             float* __restrict__ W)
{
    __shared__ __align__(16) float Xs[64 * 68];        // [d 64][n 64 +4]
    __shared__ __align__(16) float Qs[32 * 68];        // [k 32][n 64 +4]
    __shared__ __align__(16) float red4[4 * 64 * 36];  // [wave][d 64][k 32 +4]

    const int tid = threadIdx.x;
    const int bid = blockIdx.x;
    const int ns = bid & 31;
    const int dt = (bid >> 5) & 7;
    const int b  = bid >> 8;
    const int nsub = tid >> 5;
    const int dp = tid & 7;
    const int kp = (tid >> 3) & 3;
    const int wv = tid >> 6;

    float acc[8][8];
#pragma unroll
    for (int i = 0; i < 8; ++i)
#pragma unroll
        for (int j = 0; j < 8; ++j) acc[i][j] = 0.f;

    const float* xsrc = X + ((size_t)b * D_DIM + dt * 64) * N_DIM + ns * 128;
    const float* qsrc = Qin + ((size_t)b * N_DIM + ns * 128) * K_DIM;

    for (int ch = 0; ch < 2; ++ch) {   // 2 chunks of 64 n
        __syncthreads();
#pragma unroll
        for (int i = 0; i < 4; ++i) {  // stage Xs: 64 d x 64 n
            int flat4 = tid + (i << 8);
            int row = flat4 >> 4;
            int c4  = (flat4 & 15) << 2;
            float4 v = *(const float4*)(xsrc + (size_t)row * N_DIM + (ch << 6) + c4);
            *(float4*)(&Xs[row * 68 + c4]) = v;
        }
#pragma unroll
        for (int i = 0; i < 2; ++i) {  // stage Qs transposed: [k][n]
            int flat4 = tid + (i << 8);
            int nn = flat4 >> 3;
            int k4 = (flat4 & 7) << 2;
            float4 v = *(const float4*)(qsrc + ((ch << 6) + nn) * K_DIM + k4);
            Qs[(k4 + 0) * 68 + nn] = v.x;
            Qs[(k4 + 1) * 68 + nn] = v.y;
            Qs[(k4 + 2) * 68 + nn] = v.z;
            Qs[(k4 + 3) * 68 + nn] = v.w;
        }
        __syncthreads();
#pragma unroll
        for (int s = 0; s < 2; ++s) {
            const int nb = (nsub << 3) + (s << 2);
            float4 xr[8], qr[8];
#pragma unroll
            for (int i = 0; i < 8; ++i)
                xr[i] = *(const float4*)(&Xs[(dp + (i << 3)) * 68 + nb]);
#pragma unroll
            for (int j = 0; j < 8; ++j)
                qr[j] = *(const float4*)(&Qs[(kp + (j << 2)) * 68 + nb]);
#pragma unroll
            for (int i = 0; i < 8; ++i)
#pragma unroll
                for (int j = 0; j < 8; ++j) {
                    acc[i][j] = fmaf(xr[i].x, qr[j].x, acc[i][j]);
                    acc[i][j] = fmaf(xr[i].y, qr[j].y, acc[i][j]);
                    acc[i][j] = fmaf(xr[i].z, qr[j].z, acc[i][j]);
                    acc[i][j] = fmaf(xr[i].w, qr[j].w, acc[i][j]);
                }
        }
    }
    // pair-reduce nsub (2w, 2w+1) via shfl, then per-wave slabs (no atomics)
    __syncthreads();
#pragma unroll
    for (int i = 0; i < 8; ++i)
#pragma unroll
        for (int j = 0; j < 8; ++j)
            acc[i][j] += __shfl_xor(acc[i][j], 32);
    if ((tid & 32) == 0) {
#pragma unroll
        for (int i = 0; i < 8; ++i)
#pragma unroll
            for (int j = 0; j < 8; ++j)
                red4[(wv * 64 + dp + (i << 3)) * 36 + kp + (j << 2)] = acc[i][j];
    }
    __syncthreads();
    // sum 4 wave slabs, store 64x32 tile (coalesced)
    float* dst = W + WS_TP_OFF + (((size_t)ns * 2 + b) * D_DIM + dt * 64) * K_DIM;
#pragma unroll
    for (int e = 0; e < 8; ++e) {
        int flat = tid + (e << 8);          // 2048 cells
        int dl = flat >> 5;
        int k  = flat & 31;
        float s = red4[(0 * 64 + dl) * 36 + k] + red4[(1 * 64 + dl) * 36 + k]
                + red4[(2 * 64 + dl) * 36 + k] + red4[(3 * 64 + dl) * 36 + k];
        dst[dl * K_DIM + k] = s;
    }
}

// ---------------------------------------------------------------------------
// K3 (merged zpre+zfin): M from Mp partials, T from 32 TP partials,
// z = s*(T/M - c) kept in registers, nsq atomics, counter-based grid spin
// (128 tiny blocks -> trivially co-resident), then Z = z * rsqrt(nsq).
// grid 128 = b(2) x 64 d-slices of 8.
// ---------------------------------------------------------------------------
__global__ __launch_bounds__(256)
void k_zfin(const float* __restrict__ CW, const float* __restrict__ SC,
            float* __restrict__ W, float* __restrict__ Z)
{
    __shared__ float mred[8][33];
    __shared__ float Msh[K_DIM];
    __shared__ float part[8][33];

    const int tid = threadIdx.x;
    const int b  = blockIdx.x >> 6;
    const int ds = blockIdx.x & 63;
    const int g  = tid >> 5;
    const int d  = (ds << 3) + g;
    const int k  = tid & 31;

    float* nsq = W;
    int*   cnt = (int*)(W + 64);
    const float* Mp = W + WS_MP_OFF;
    const float* TP = W + WS_TP_OFF;

    // M[b,k] = sum over 256 n-tiles of Mp (L2-hot, coalesced across k)
    float pm = 0.f;
#pragma unroll
    for (int i = 0; i < 32; ++i)
        pm += Mp[((b << 8) + (g << 5) + i) * K_DIM + k];
    mred[g][k] = pm;
    __syncthreads();
    if (tid < K_DIM) {
        float t = 0.f;
#pragma unroll
        for (int i = 0; i < 8; ++i) t += mred[i][tid];
        Msh[tid] = t;
    }
    __syncthreads();
    const float m = Msh[k];

    // T[b,d,k] = sum of 32 n-slice partials (L2-hot, coalesced across k)
    float sum = 0.f;
#pragma unroll
    for (int ns = 0; ns < 32; ++ns)
        sum += TP[(((size_t)ns * 2 + b) * D_DIM + d) * K_DIM + k];

    const float c = CW[k * D_DIM + d];
    const float s = SC[d * K_DIM + k];
    const float z = s * (sum / m - c);

    part[g][k] = z * z;
    __syncthreads();
    if (tid < K_DIM) {
        float q = 0.f;
#pragma unroll
        for (int i = 0; i < 8; ++i) q += part[i][tid];
        atomicAdd(&nsq[(b << 5) + tid], q);
    }

    // ---- grid sync: all 128 blocks' nsq contributions must land ----
    __threadfence();
    __syncthreads();
    if (tid == 0) {
        __hip_atomic_fetch_add(cnt, 1, __ATOMIC_ACQ_REL, __HIP_MEMORY_SCOPE_AGENT);
        while (__hip_atomic_load(cnt, __ATOMIC_ACQUIRE, __HIP_MEMORY_SCOPE_AGENT)
               < (int)gridDim.x)
            __builtin_amdgcn_s_sleep(2);
    }
    __syncthreads();

    const float nv = __hip_atomic_load(&nsq[(b << 5) + k], __ATOMIC_RELAXED,
                                       __HIP_MEMORY_SCOPE_AGENT);
    Z[((size_t)(b * D_DIM + d)) * K_DIM + k] = z * rsqrtf(nv);
}

extern "C" void kernel_launch(void* const* d_in, const int* in_sizes, int n_in,
                              void* d_out, int out_size, void* d_ws, size_t ws_size,
                              hipStream_t stream)
{
    const float* X  = (const float*)d_in[0];   // [2,512,64,64]
    const float* CW = (const float*)d_in[1];   // [32,512]
    const float* SC = (const float*)d_in[2];   // [512,32]
    float* Z = (float*)d_out;                              // [2,512,32]
    float* Q = (float*)d_out + B_DIM * D_DIM * K_DIM;      // [2,4096,32]
    float* W = (float*)d_ws;

    k_dist_q<<<512, 256, 0, stream>>>(X, CW, SC, Q, W);
    k_tpart <<<512, 256, 0, stream>>>(X, Q, W);
    k_zfin  <<<128, 256, 0, stream>>>(CW, SC, W, Z);
}

// Round 3
// 97.306 us; speedup vs baseline: 1.1000x; 1.0995x over previous
//
#include <hip/hip_runtime.h>
#include <math.h>

// Problem constants (B=2, D=512, K=32, H=W=64 -> N=4096)
#define B_DIM 2
#define D_DIM 512
#define K_DIM 32
#define N_DIM 4096

// Workspace layout (floats):
//   [0:64)      nsq[b][k]          (atomicAdd by k_zpre; zeroed by k1 blk 0)
//   [64:128)    pad
//   [128:128+16384)   Mp[b*256+tile][k]   (per-block Q mass from k1)
//   then        TP[ns*2+b][d][k]          (32 n-slice partials from k2, 4 MB)
//   then        Ztmp[b][d][k]             (32768 floats)
#define WS_MP_OFF  128
#define WS_TP_OFF  (128 + 512 * K_DIM)
#define WS_ZT_OFF  (WS_TP_OFF + 32 * B_DIM * D_DIM * K_DIM)

// ---------------------------------------------------------------------------
// K1: distances + softmax Q + per-block Q-mass partial Mp. Zeroes nsq.
// dist[b,n,k] = sum_d A*x^2 + B2*x + A*c^2,  A = s^2, B2 = -2 s^2 c
// grid = 512 = B * 256 n-tiles of 16; block = 256 threads (4 waves)
// Thread (dp = tid&63, kp = tid>>6) owns d-slice {4dp..4dp+3, 256+4dp..+3}
// and k-slice [8kp, 8kp+8). A/B2 in registers; x streamed from LDS.
// ---------------------------------------------------------------------------
__global__ __launch_bounds__(256, 2)
void k_dist_q(const float* __restrict__ X, const float* __restrict__ CW,
              const float* __restrict__ SC, float* __restrict__ Qout,
              float* __restrict__ W)
{
    __shared__ __align__(16) float xlds[16 * 516];     // [n 16][d 512, stride 516]
    __shared__ __align__(16) float red[16 * 16 * 36];  // [n 16][i 16][k 32 +4]

    const int tid = threadIdx.x;
    const int b  = blockIdx.x >> 8;
    const int n0 = (blockIdx.x & 255) << 4;   // 16 n per block
    const int dp = tid & 63;
    const int kp = tid >> 6;
    const int k0 = kp << 3;

    // zero nsq; consumed 2 dispatches later (stream-ordered)
    if (blockIdx.x == 0 && tid < 64) W[tid] = 0.f;

    // ---- stage 16 n x 512 d (transposed to [n][d]); 64-B coalesced reads ----
    const float* xsrc = X + (size_t)b * D_DIM * N_DIM + n0;
#pragma unroll
    for (int j = 0; j < 8; ++j) {
        const int d  = (tid >> 2) + (j << 6);
        const int n4 = (tid & 3) << 2;
        float4 v = *(const float4*)(xsrc + (size_t)d * N_DIM + n4);
        xlds[(n4 + 0) * 516 + d] = v.x;
        xlds[(n4 + 1) * 516 + d] = v.y;
        xlds[(n4 + 2) * 516 + d] = v.z;
        xlds[(n4 + 3) * 516 + d] = v.w;
    }

    // ---- prologue: register tables (overlaps other waves' staging) ----
    float cv[8][8];                    // cv[kk][dd] = codeword value
#pragma unroll
    for (int kk = 0; kk < 8; ++kk) {
        const float* cr = CW + (k0 + kk) * D_DIM + (dp << 2);
        float4 c0 = *(const float4*)(cr);
        float4 c1 = *(const float4*)(cr + 256);
        cv[kk][0] = c0.x; cv[kk][1] = c0.y; cv[kk][2] = c0.z; cv[kk][3] = c0.w;
        cv[kk][4] = c1.x; cv[kk][5] = c1.y; cv[kk][6] = c1.z; cv[kk][7] = c1.w;
    }
    float Areg[8][8], Breg[8][8], ckp[8];
#pragma unroll
    for (int kk = 0; kk < 8; ++kk) ckp[kk] = 0.f;
#pragma unroll
    for (int dd = 0; dd < 8; ++dd) {
        const int d = (dd < 4) ? ((dp << 2) + dd) : (256 + (dp << 2) + (dd - 4));
        float4 s0 = *(const float4*)(SC + d * K_DIM + k0);
        float4 s1 = *(const float4*)(SC + d * K_DIM + k0 + 4);
        float sv[8] = {s0.x, s0.y, s0.z, s0.w, s1.x, s1.y, s1.z, s1.w};
#pragma unroll
        for (int kk = 0; kk < 8; ++kk) {
            float c = cv[kk][dd];
            float a = sv[kk] * sv[kk];
            Areg[dd][kk] = a;
            Breg[dd][kk] = -2.f * a * c;
            ckp[kk] = fmaf(a * c, c, ckp[kk]);
        }
    }
    __syncthreads();

    // ---- main: 16 n, 128 FMA-pairs each ----
#pragma unroll
    for (int n = 0; n < 16; ++n) {
        float dist[8];
#pragma unroll
        for (int kk = 0; kk < 8; ++kk) dist[kk] = ckp[kk];
        float4 xa = *(const float4*)(&xlds[n * 516 + (dp << 2)]);
        float4 xb = *(const float4*)(&xlds[n * 516 + (dp << 2) + 256]);
        float xv[8] = {xa.x, xa.y, xa.z, xa.w, xb.x, xb.y, xb.z, xb.w};
#pragma unroll
        for (int dd = 0; dd < 8; ++dd) {
            const float x  = xv[dd];
            const float x2 = x * x;
#pragma unroll
            for (int kk = 0; kk < 8; ++kk) {
                dist[kk] = fmaf(Areg[dd][kk], x2, dist[kk]);
                dist[kk] = fmaf(Breg[dd][kk], x,  dist[kk]);
            }
        }
#pragma unroll
        for (int kk = 0; kk < 8; ++kk) {
            dist[kk] += __shfl_xor(dist[kk], 32);
            dist[kk] += __shfl_xor(dist[kk], 16);
        }
        if (dp < 16) {
            float* r = &red[(n * 16 + dp) * 36 + k0];
            *(float4*)(r)     = make_float4(dist[0], dist[1], dist[2], dist[3]);
            *(float4*)(r + 4) = make_float4(dist[4], dist[5], dist[6], dist[7]);
        }
    }
    __syncthreads();

    // ---- reduce 16 partials + softmax over k (32-lane groups), 2 passes ----
    // xlds is dead past this sync: reuse as mq[16][33] for the Q-mass partial.
#pragma unroll
    for (int h = 0; h < 2; ++h) {
        const int n = (tid >> 5) + (h << 3);
        const int k = tid & 31;
        float dsum = 0.f;
#pragma unroll
        for (int i = 0; i < 16; ++i) dsum += red[(n * 16 + i) * 36 + k];
        float m = dsum;
#pragma unroll
        for (int mk = 16; mk >= 1; mk >>= 1)
            m = fminf(m, __shfl_xor(m, mk));
        float e = __expf(-0.5f * (dsum - m));
        float ssum = e;
#pragma unroll
        for (int mk = 16; mk >= 1; mk >>= 1)
            ssum += __shfl_xor(ssum, mk);
        float q = __fdividef(e, ssum);
        Qout[((size_t)b * N_DIM + n0 + n) * K_DIM + k] = q;
        xlds[n * 33 + k] = q;
    }
    __syncthreads();
    if (tid < K_DIM) {
        float t = 0.f;
#pragma unroll
        for (int i = 0; i < 16; ++i) t += xlds[i * 33 + tid];
        W[WS_MP_OFF + blockIdx.x * K_DIM + tid] = t;
    }
}

// ---------------------------------------------------------------------------
// K2: T partials. T[b,d,k] = sum_n Q[b,n,k] * X[b,d,n], n split 32 ways.
// grid = 512 = b(2) x dtile(8 of 64 d) x ns(32 of 128 n). Plain stores to TP
// (no atomics). Round-0 structure; Mpart tail removed (Mp comes from k1).
// ---------------------------------------------------------------------------
__global__ __launch_bounds__(256, 2)
void k_tpart(const float* __restrict__ X, const float* __restrict__ Qin,
             float* __restrict__ W)
{
    __shared__ __align__(16) float Xs[64 * 68];        // [d 64][n 64 +4]
    __shared__ __align__(16) float Qs[32 * 68];        // [k 32][n 64 +4]
    __shared__ __align__(16) float red4[4 * 64 * 36];  // [wave][d 64][k 32 +4]

    const int tid = threadIdx.x;
    const int bid = blockIdx.x;
    const int ns = bid & 31;
    const int dt = (bid >> 5) & 7;
    const int b  = bid >> 8;
    const int nsub = tid >> 5;
    const int dp = tid & 7;
    const int kp = (tid >> 3) & 3;
    const int wv = tid >> 6;

    float acc[8][8];
#pragma unroll
    for (int i = 0; i < 8; ++i)
#pragma unroll
        for (int j = 0; j < 8; ++j) acc[i][j] = 0.f;

    const float* xsrc = X + ((size_t)b * D_DIM + dt * 64) * N_DIM + ns * 128;
    const float* qsrc = Qin + ((size_t)b * N_DIM + ns * 128) * K_DIM;

    for (int ch = 0; ch < 2; ++ch) {   // 2 chunks of 64 n
        __syncthreads();
#pragma unroll
        for (int i = 0; i < 4; ++i) {  // stage Xs: 64 d x 64 n
            int flat4 = tid + (i << 8);
            int row = flat4 >> 4;
            int c4  = (flat4 & 15) << 2;
            float4 v = *(const float4*)(xsrc + (size_t)row * N_DIM + (ch << 6) + c4);
            *(float4*)(&Xs[row * 68 + c4]) = v;
        }
#pragma unroll
        for (int i = 0; i < 2; ++i) {  // stage Qs transposed: [k][n]
            int flat4 = tid + (i << 8);
            int nn = flat4 >> 3;
            int k4 = (flat4 & 7) << 2;
            float4 v = *(const float4*)(qsrc + ((ch << 6) + nn) * K_DIM + k4);
            Qs[(k4 + 0) * 68 + nn] = v.x;
            Qs[(k4 + 1) * 68 + nn] = v.y;
            Qs[(k4 + 2) * 68 + nn] = v.z;
            Qs[(k4 + 3) * 68 + nn] = v.w;
        }
        __syncthreads();
#pragma unroll
        for (int s = 0; s < 2; ++s) {
            const int nb = (nsub << 3) + (s << 2);
            float4 xr[8], qr[8];
#pragma unroll
            for (int i = 0; i < 8; ++i)
                xr[i] = *(const float4*)(&Xs[(dp + (i << 3)) * 68 + nb]);
#pragma unroll
            for (int j = 0; j < 8; ++j)
                qr[j] = *(const float4*)(&Qs[(kp + (j << 2)) * 68 + nb]);
#pragma unroll
            for (int i = 0; i < 8; ++i)
#pragma unroll
                for (int j = 0; j < 8; ++j) {
                    acc[i][j] = fmaf(xr[i].x, qr[j].x, acc[i][j]);
                    acc[i][j] = fmaf(xr[i].y, qr[j].y, acc[i][j]);
                    acc[i][j] = fmaf(xr[i].z, qr[j].z, acc[i][j]);
                    acc[i][j] = fmaf(xr[i].w, qr[j].w, acc[i][j]);
                }
        }
    }
    // pair-reduce nsub (2w, 2w+1) via shfl, then per-wave slabs (no atomics)
    __syncthreads();
#pragma unroll
    for (int i = 0; i < 8; ++i)
#pragma unroll
        for (int j = 0; j < 8; ++j)
            acc[i][j] += __shfl_xor(acc[i][j], 32);
    if ((tid & 32) == 0) {
#pragma unroll
        for (int i = 0; i < 8; ++i)
#pragma unroll
            for (int j = 0; j < 8; ++j)
                red4[(wv * 64 + dp + (i << 3)) * 36 + kp + (j << 2)] = acc[i][j];
    }
    __syncthreads();
    // sum 4 wave slabs, store 64x32 tile (coalesced)
    float* dst = W + WS_TP_OFF + (((size_t)ns * 2 + b) * D_DIM + dt * 64) * K_DIM;
#pragma unroll
    for (int e = 0; e < 8; ++e) {
        int flat = tid + (e << 8);          // 2048 cells
        int dl = flat >> 5;
        int k  = flat & 31;
        float s = red4[(0 * 64 + dl) * 36 + k] + red4[(1 * 64 + dl) * 36 + k]
                + red4[(2 * 64 + dl) * 36 + k] + red4[(3 * 64 + dl) * 36 + k];
        dst[dl * K_DIM + k] = s;
    }
}

// ---------------------------------------------------------------------------
// K3: sum 32 TP partials, M from 256 Mp tiles, Z_ = s*(T/M - c); write Ztmp;
// nsq atomics. grid 128 = b(2) x 64 d-slices of 8. (Round-0 structure.)
// ---------------------------------------------------------------------------
__global__ __launch_bounds__(256)
void k_zpre(const float* __restrict__ CW, const float* __restrict__ SC,
            float* __restrict__ W)
{
    __shared__ float mred[8][33];
    __shared__ float Msh[K_DIM];
    __shared__ float part[8][33];

    const int tid = threadIdx.x;
    const int b  = blockIdx.x >> 6;
    const int ds = blockIdx.x & 63;
    const int g  = tid >> 5;
    const int d  = (ds << 3) + g;
    const int k  = tid & 31;

    float* nsq = W;
    const float* Mp = W + WS_MP_OFF;
    const float* TP = W + WS_TP_OFF;
    float* Ztmp = W + WS_ZT_OFF;

    // M[b,k] = sum over 256 n-tiles of Mp (L2-hot, coalesced across k)
    float pm = 0.f;
#pragma unroll
    for (int i = 0; i < 32; ++i)
        pm += Mp[((b << 8) + (g << 5) + i) * K_DIM + k];
    mred[g][k] = pm;
    __syncthreads();
    if (tid < K_DIM) {
        float t = 0.f;
#pragma unroll
        for (int i = 0; i < 8; ++i) t += mred[i][tid];
        Msh[tid] = t;
    }
    __syncthreads();
    const float m = Msh[k];

    // T[b,d,k] = sum of 32 n-slice partials (L2-hot, coalesced across k)
    float sum = 0.f;
#pragma unroll
    for (int ns = 0; ns < 32; ++ns)
        sum += TP[(((size_t)ns * 2 + b) * D_DIM + d) * K_DIM + k];

    const float c = CW[k * D_DIM + d];
    const float s = SC[d * K_DIM + k];
    const float z = s * (sum / m - c);
    Ztmp[((size_t)(b * D_DIM + d)) * K_DIM + k] = z;

    part[g][k] = z * z;
    __syncthreads();
    if (tid < K_DIM) {
        float q = 0.f;
#pragma unroll
        for (int i = 0; i < 8; ++i) q += part[i][tid];
        atomicAdd(&nsq[(b << 5) + tid], q);
    }
}

// K4: Z = Ztmp * rsqrt(nsq)
__global__ __launch_bounds__(256)
void k_zfin(const float* __restrict__ W, float* __restrict__ Z)
{
    const int tid = threadIdx.x;
    const int b  = blockIdx.x >> 6;
    const int ds = blockIdx.x & 63;
    const int d  = (ds << 3) + (tid >> 5);
    const int k  = tid & 31;
    const float* nsq = W;
    const float* Ztmp = W + WS_ZT_OFF;
    const int idx = ((b * D_DIM) + d) * K_DIM + k;
    Z[idx] = Ztmp[idx] * rsqrtf(nsq[(b << 5) + k]);
}

extern "C" void kernel_launch(void* const* d_in, const int* in_sizes, int n_in,
                              void* d_out, int out_size, void* d_ws, size_t ws_size,
                              hipStream_t stream)
{
    const float* X  = (const float*)d_in[0];   // [2,512,64,64]
    const float* CW = (const float*)d_in[1];   // [32,512]
    const float* SC = (const float*)d_in[2];   // [512,32]
    float* Z = (float*)d_out;                              // [2,512,32]
    float* Q = (float*)d_out + B_DIM * D_DIM * K_DIM;      // [2,4096,32]
    float* W = (float*)d_ws;

    k_dist_q<<<512, 256, 0, stream>>>(X, CW, SC, Q, W);
    k_tpart <<<512, 256, 0, stream>>>(X, Q, W);
    k_zpre  <<<128, 256, 0, stream>>>(CW, SC, W);
    k_zfin  <<<128, 256, 0, stream>>>(W, Z);
}